// Round 11
// baseline (196.351 us; speedup 1.0000x reference)
//
#include <hip/hip_runtime.h>

// ---------------- problem constants ----------------
#define DIMC 1024
#define NH   16
#define HD   64
#define BSZ  2
#define TSZ  2048
#define MROWS (BSZ*TSZ)   // 4096

typedef __attribute__((ext_vector_type(8))) short s16x8;   // 8 bf16 (4 VGPRs)
typedef __attribute__((ext_vector_type(4))) float f32x4;   // 4 fp32

__device__ __forceinline__ float b2f(unsigned short u) {
  return __uint_as_float(((unsigned)u) << 16);
}
__device__ __forceinline__ unsigned short f2b(float f) {
  unsigned x = __float_as_uint(f);
  unsigned r = x + 0x7fffu + ((x >> 16) & 1u);   // RTNE
  return (unsigned short)(r >> 16);
}
__device__ __forceinline__ unsigned pk2(float a, float b) {
  return (unsigned)f2b(a) | ((unsigned)f2b(b) << 16);
}
__device__ __forceinline__ float ldsc(const void* __restrict__ p, int idx, int isf32) {
  return isf32 ? ((const float*)p)[idx] : b2f(((const unsigned short*)p)[idx]);
}

// 16-byte global -> LDS DMA. lds base wave-uniform; HW writes lane i at base+16i.
__device__ __forceinline__ void async_cp16(const unsigned short* g, unsigned short* l) {
  __builtin_amdgcn_global_load_lds(
      (const __attribute__((address_space(1))) unsigned int*)g,
      (__attribute__((address_space(3))) unsigned int*)l, 16, 0, 0);
}

// ---------------------------------------------------------------------------
__global__ void detect_dtype(const unsigned short* __restrict__ cosp, int* __restrict__ flag) {
  const int i = threadIdx.x;   // 64 threads
  const unsigned long long m = __ballot(cosp[i] >= 0x4000u);
  if (i == 0) *flag = (m != 0ull) ? 1 : 0;
}

// ---------------------------------------------------------------------------
// One-shot fp32 -> bf16 conversion of x, w_qkv, w_out (only when inputs fp32).
// ---------------------------------------------------------------------------
__global__ __launch_bounds__(256)
void cvt_all(const float* __restrict__ x, const float* __restrict__ wq,
             const float* __restrict__ wo,
             unsigned short* __restrict__ xb, unsigned short* __restrict__ wqb,
             unsigned short* __restrict__ wob, const int* __restrict__ flag) {
  if (*flag == 0) return;
  const unsigned id = blockIdx.x * 256 + threadIdx.x;  // 0..1048575
  const float* src; unsigned short* dst; unsigned off;
  if (id < 524288u) { src = x; dst = xb; off = id; }
  else if (id < 917504u) { src = wq; dst = wqb; off = id - 524288u; }
  else { src = wo; dst = wob; off = id - 917504u; }
  const float4 a = ((const float4*)src)[off * 2];
  const float4 b = ((const float4*)src)[off * 2 + 1];
  uint4 u;
  u.x = pk2(a.x, a.y); u.y = pk2(a.z, a.w);
  u.z = pk2(b.x, b.y); u.w = pk2(b.z, b.w);
  ((uint4*)dst)[off] = u;
}

// ---------------------------------------------------------------------------
// MFMA bf16 GEMM (async staging):  C[M,N] = A[M,K] @ W[N,K]^T, bf16 operands.
// M-tile 128, N-tile 64, BK=64, K=1024. Wave w: rows w*32..+32 x all 64 cols,
// acc[2][4]. QKV 1536 blocks / out-proj 512 -> multi-block/CU co-residency
// hides the global_load_lds vmcnt(0) barrier drain. LDS 24 KB unpadded,
// XOR-swizzled (0 conflicts measured R7).
// EPI=0: store C[M,N] (fp32 if f32flag else bf16).
// EPI=1: RoPE (+0.125 q-scale), LDS round-trip, coalesced uint4 scatter.
// ---------------------------------------------------------------------------
template <int EPI>
__global__ __launch_bounds__(256)
void gemm_bt_async(const void* __restrict__ Aorig, const unsigned short* __restrict__ Aconv,
                   const void* __restrict__ Worig, const unsigned short* __restrict__ Wconv,
                   void* __restrict__ C,
                   const void* __restrict__ cosp, const void* __restrict__ sinp,
                   unsigned short* __restrict__ qout,
                   unsigned short* __restrict__ kout,
                   unsigned short* __restrict__ vout,
                   const int* __restrict__ dflag, int Nsz) {
  const int f32flag = *dflag;
  const unsigned short* A = f32flag ? Aconv : (const unsigned short*)Aorig;
  const unsigned short* W = f32flag ? Wconv : (const unsigned short*)Worig;

  const int tid = threadIdx.x;
  const int m0 = blockIdx.y * 128;
  const int n0 = blockIdx.x * 64;

  __shared__ __align__(16) unsigned short s_ab[128 * 64 + 64 * 64];  // 24 KB
  unsigned short* s_a = s_ab;
  unsigned short* s_b = s_ab + 128 * 64;

  const int lane = tid & 63;
  const int wave = tid >> 6;
  const int wm = wave * 32;
  const int m16 = lane & 15;
  const int quad = lane >> 4;

  const int srow = lane >> 3;
  const int schunk = (lane & 7) ^ srow;

  f32x4 acc[2][4];
#pragma unroll
  for (int i = 0; i < 2; ++i)
#pragma unroll
    for (int j = 0; j < 4; ++j) acc[i][j] = (f32x4){0.f, 0.f, 0.f, 0.f};

  for (int kt = 0; kt < DIMC; kt += 64) {
    __syncthreads();
#pragma unroll
    for (int u = 0; u < 4; ++u) {          // A: 128 rows
      const int r0 = u * 32 + wave * 8;
      async_cp16(A + (size_t)(m0 + r0 + srow) * DIMC + kt + schunk * 8, &s_a[r0 * 64]);
    }
#pragma unroll
    for (int u = 0; u < 2; ++u) {          // B: 64 rows
      const int r0 = u * 32 + wave * 8;
      async_cp16(W + (size_t)(n0 + r0 + srow) * DIMC + kt + schunk * 8, &s_b[r0 * 64]);
    }
    __syncthreads();
#pragma unroll
    for (int kk = 0; kk < 64; kk += 32) {
      const int cx = ((kk >> 3) + quad) ^ (m16 & 7);
      s16x8 af[2], bf[4];
#pragma unroll
      for (int i = 0; i < 2; ++i)
        af[i] = *(const s16x8*)&s_a[(wm + i * 16 + m16) * 64 + cx * 8];
#pragma unroll
      for (int j = 0; j < 4; ++j)
        bf[j] = *(const s16x8*)&s_b[(j * 16 + m16) * 64 + cx * 8];
#pragma unroll
      for (int i = 0; i < 2; ++i)
#pragma unroll
        for (int j = 0; j < 4; ++j)
          acc[i][j] = __builtin_amdgcn_mfma_f32_16x16x32_bf16(af[i], bf[j], acc[i][j], 0, 0, 0);
    }
  }

  // Epilogue. C/D layout: col = lane&15 (tile j), row = quad*4 + reg.
  if (EPI == 1) {
    const int sel = n0 >> 10;              // 0=q 1=k 2=v (block-uniform)
    const int h = (n0 & 1023) >> 6;
    unsigned short* dst = (sel == 0) ? qout : ((sel == 1) ? kout : vout);
    const float qsc = (sel == 0) ? 0.125f : 1.0f;
    __syncthreads();                       // s_ab dead; reuse as transpose tile
    unsigned short* tile = s_ab + wave * 2048;    // 32x64 u16 per wave
    if (sel < 2) {                         // q/k: RoPE in-register
#pragma unroll
      for (int i = 0; i < 2; ++i)
#pragma unroll
        for (int r = 0; r < 4; ++r) {
          const int row_l = i * 16 + quad * 4 + r;        // 0..31
          const int t = (m0 + wm + row_l) & 2047;
#pragma unroll
          for (int jp = 0; jp < 2; ++jp) {
            const int d = jp * 16 + m16;   // 0..31
            const float c = ldsc(cosp, t * 32 + d, f32flag);
            const float sn = ldsc(sinp, t * 32 + d, f32flag);
            const float v1 = acc[i][jp][r];
            const float v2 = acc[i][jp + 2][r];
            tile[row_l * 64 + d]      = f2b((v1 * c - v2 * sn) * qsc);
            tile[row_l * 64 + d + 32] = f2b((v1 * sn + v2 * c) * qsc);
          }
        }
    } else {
#pragma unroll
      for (int i = 0; i < 2; ++i)
#pragma unroll
        for (int r = 0; r < 4; ++r) {
          const int row_l = i * 16 + quad * 4 + r;
#pragma unroll
          for (int jp = 0; jp < 4; ++jp)
            tile[row_l * 64 + jp * 16 + m16] = f2b(acc[i][jp][r]);
        }
    }
#pragma unroll
    for (int s = 0; s < 4; ++s) {
      const int row_l = s * 8 + (lane >> 3);
      const int seg = lane & 7;
      const int mrow_ = m0 + wm + row_l;
      const int bb = mrow_ >> 11;
      const int t = mrow_ & 2047;
      unsigned short* drow = dst + (((size_t)(bb * NH + h)) * TSZ + t) * HD;
      *(uint4*)(drow + seg * 8) = *(const uint4*)&tile[row_l * 64 + seg * 8];
    }
  } else {
    if (f32flag) {
      float* Cf = (float*)C;
#pragma unroll
      for (int i = 0; i < 2; ++i)
#pragma unroll
        for (int j = 0; j < 4; ++j)
#pragma unroll
          for (int r = 0; r < 4; ++r) {
            const int mrow_ = m0 + wm + i * 16 + quad * 4 + r;
            const int col = n0 + j * 16 + m16;
            Cf[(size_t)mrow_ * Nsz + col] = acc[i][j][r];
          }
    } else {
      unsigned short* Ch = (unsigned short*)C;
#pragma unroll
      for (int i = 0; i < 2; ++i)
#pragma unroll
        for (int j = 0; j < 4; ++j)
#pragma unroll
          for (int r = 0; r < 4; ++r) {
            const int mrow_ = m0 + wm + i * 16 + quad * 4 + r;
            const int col = n0 + j * 16 + m16;
            Ch[(size_t)mrow_ * Nsz + col] = f2b(acc[i][j][r]);
          }
    }
  }
}

// ---------------------------------------------------------------------------
// MFMA flash attention, S^T form, q-tile 128, 512 threads (8 waves).
// LDS: unpadded stride-64 rows, chunk-XOR swizzle (GEMM-proven 0-conflict):
//   element (row, c-chunk) lives at row*64 + (c ^ (row&7))*8.
// 48 KB total -> 3 blocks/CU. 512 single-tile blocks, longest-first (LPT).
// Double-buffered K/V: one barrier per chunk.
// ---------------------------------------------------------------------------
__device__ __forceinline__ void attn_pass(
    const unsigned short* __restrict__ qgh, const unsigned short* __restrict__ kgh,
    const unsigned short* __restrict__ vgh, unsigned short* __restrict__ outg,
    int b, int h, int t, unsigned short* s_k0, unsigned short* s_k1,
    unsigned short* s_v0, unsigned short* s_v1, unsigned short* s_p,
    int tid, int lane, int w, int m16, int quad) {
  const int qs = t * 128 + w * 16;         // wave's first query (global)
  const unsigned short* qrow = qgh + (size_t)(qs + m16) * HD;
  const s16x8 bq0 = *(const s16x8*)(qrow + quad * 8);
  const s16x8 bq1 = *(const s16x8*)(qrow + 32 + quad * 8);

  f32x4 oacc[4];
#pragma unroll
  for (int dt = 0; dt < 4; ++dt) oacc[dt] = (f32x4){0.f, 0.f, 0.f, 0.f};
  float m_ = -1e30f, l_ = 0.f;

  const int krow = tid >> 3, kseg = tid & 7;   // K staging: 64 rows x 8 chunks
  const int kpos = kseg ^ (krow & 7);          // XOR-swizzled chunk slot
  const int vkey = tid & 63, vseg = tid >> 6;  // V staging: 64 keys x 8 d-rows
  const int prow = (w * 16 + m16) * 64;        // wave-private P/O row base
  const int pm7 = m16 & 7;
  const int nc = 2 * t + 2;

  {  // prologue: chunk 0 into buf0
    const uint4 pk = *(const uint4*)(kgh + (size_t)krow * HD + kseg * 8);
    const uint4 pv = *(const uint4*)(vgh + (size_t)vkey * HD + vseg * 8);
    *(uint4*)&s_k0[krow * 64 + kpos * 8] = pk;
    const unsigned short* vv = (const unsigned short*)&pv;
#pragma unroll
    for (int jj = 0; jj < 8; ++jj) {
      const int d = vseg * 8 + jj;
      s_v0[d * 64 + ((vkey >> 3) ^ (d & 7)) * 8 + (vkey & 7)] = vv[jj];
    }
  }

  for (int kc = 0; kc < nc; ++kc) {
    unsigned short* sk = (kc & 1) ? s_k1 : s_k0;
    unsigned short* sv = (kc & 1) ? s_v1 : s_v0;
    unsigned short* skN = (kc & 1) ? s_k0 : s_k1;
    unsigned short* svN = (kc & 1) ? s_v0 : s_v1;
    __syncthreads();                       // buf[kc] ready; buf[kc+1] free
    uint4 pk, pv;
    const int pf = (kc + 1 < nc);
    if (pf) {                              // prefetch next chunk (overlaps compute)
      pk = *(const uint4*)(kgh + (size_t)((kc + 1) * 64 + krow) * HD + kseg * 8);
      pv = *(const uint4*)(vgh + (size_t)((kc + 1) * 64 + vkey) * HD + vseg * 8);
    }

    if (kc * 64 <= qs + 15) {              // not fully masked for this wave
      f32x4 sacc[4];
#pragma unroll
      for (int jt = 0; jt < 4; ++jt) sacc[jt] = (f32x4){0.f, 0.f, 0.f, 0.f};
#pragma unroll
      for (int kk = 0; kk < 64; kk += 32) {
        const int cx = ((kk >> 3) + quad) ^ pm7;
        const s16x8 bq = (kk == 0) ? bq0 : bq1;
#pragma unroll
        for (int jt = 0; jt < 4; ++jt) {
          const s16x8 ak = *(const s16x8*)&sk[(jt * 16 + m16) * 64 + cx * 8];
          sacc[jt] = __builtin_amdgcn_mfma_f32_16x16x32_bf16(ak, bq, sacc[jt], 0, 0, 0);
        }
      }

      if (kc * 64 + 63 > qs) {             // diagonal region: element mask
#pragma unroll
        for (int jt = 0; jt < 4; ++jt)
#pragma unroll
          for (int r = 0; r < 4; ++r)
            if (kc * 64 + jt * 16 + quad * 4 + r > qs + m16) sacc[jt][r] = -1e30f;
      }

      float mx = sacc[0][0];
#pragma unroll
      for (int jt = 0; jt < 4; ++jt)
#pragma unroll
        for (int r = 0; r < 4; ++r) mx = fmaxf(mx, sacc[jt][r]);
      mx = fmaxf(mx, __shfl_xor(mx, 16, 64));
      mx = fmaxf(mx, __shfl_xor(mx, 32, 64));
      const float mn = fmaxf(m_, mx);
      const float alpha = __expf(m_ - mn);
      m_ = mn;
      float rs = 0.f;
#pragma unroll
      for (int jt = 0; jt < 4; ++jt)
#pragma unroll
        for (int r = 0; r < 4; ++r) {
          const float p = __expf(sacc[jt][r] - mn);
          sacc[jt][r] = p;
          rs += p;
        }
      rs += __shfl_xor(rs, 16, 64);
      rs += __shfl_xor(rs, 32, 64);
      l_ = l_ * alpha + rs;
#pragma unroll
      for (int dt = 0; dt < 4; ++dt)
#pragma unroll
        for (int r = 0; r < 4; ++r) oacc[dt][r] *= alpha;

      // P -> s_p[query][key], uint2, XOR-swizzled chunks
#pragma unroll
      for (int jt = 0; jt < 4; ++jt) {
        uint2 pw;
        pw.x = pk2(sacc[jt][0], sacc[jt][1]);
        pw.y = pk2(sacc[jt][2], sacc[jt][3]);
        const int pc = (2 * jt + (quad >> 1)) ^ pm7;
        *(uint2*)&s_p[prow + pc * 8 + (quad & 1) * 4] = pw;
      }

#pragma unroll
      for (int kk = 0; kk < 64; kk += 32) {
        const int cx = ((kk >> 3) + quad) ^ pm7;
        const s16x8 bp = *(const s16x8*)&s_p[prow + cx * 8];
#pragma unroll
        for (int dt = 0; dt < 4; ++dt) {
          const s16x8 av = *(const s16x8*)&sv[(dt * 16 + m16) * 64 + cx * 8];
          oacc[dt] = __builtin_amdgcn_mfma_f32_16x16x32_bf16(av, bp, oacc[dt], 0, 0, 0);
        }
      }
    }

    if (pf) {                              // store next chunk into other buffer
      *(uint4*)&skN[krow * 64 + kpos * 8] = pk;
      const unsigned short* vv = (const unsigned short*)&pv;
#pragma unroll
      for (int jj = 0; jj < 8; ++jj) {
        const int d = vseg * 8 + jj;
        svN[d * 64 + ((vkey >> 3) ^ (d & 7)) * 8 + (vkey & 7)] = vv[jj];
      }
    }
  }

  // epilogue: normalize, transpose via wave-private s_p rows, coalesced store
  const float linv = 1.0f / l_;
#pragma unroll
  for (int dt = 0; dt < 4; ++dt) {
    uint2 ow;
    ow.x = pk2(oacc[dt][0] * linv, oacc[dt][1] * linv);
    ow.y = pk2(oacc[dt][2] * linv, oacc[dt][3] * linv);
    const int pc = (2 * dt + (quad >> 1)) ^ pm7;
    *(uint2*)&s_p[prow + pc * 8 + (quad & 1) * 4] = ow;
  }
  {
    const int qq = lane >> 2, dseg = lane & 3;   // wave-private rows: no barrier
    const int rbase = (w * 16 + qq) * 64;
    const int q7 = qq & 7;
    const uint4 o0 = *(const uint4*)&s_p[rbase + ((2 * dseg) ^ q7) * 8];
    const uint4 o1 = *(const uint4*)&s_p[rbase + ((2 * dseg + 1) ^ q7) * 8];
    unsigned short* orow =
        outg + ((size_t)b * TSZ + qs + qq) * DIMC + h * 64 + dseg * 16;
    *(uint4*)orow = o0;
    *(uint4*)(orow + 8) = o1;
  }
}

__global__ __launch_bounds__(512)
void attn_fwd_mfma(const unsigned short* __restrict__ qg,
                   const unsigned short* __restrict__ kg,
                   const unsigned short* __restrict__ vg,
                   unsigned short* __restrict__ outg) {
  const int tid = threadIdx.x;
  const int lane = tid & 63;
  const int w = tid >> 6;                // wave 0..7
  const int m16 = lane & 15;
  const int quad = lane >> 4;
  const int l = (int)blockIdx.x;         // 0..511
  const int t = 15 - (l >> 5);           // longest tiles dispatched first (LPT)
  const int bh = l & 31;
  const int b = bh >> 4, h = bh & 15;
  const size_t base = (size_t)bh * TSZ * HD;

  __shared__ __align__(16) unsigned short s_k0[64 * 64];
  __shared__ __align__(16) unsigned short s_k1[64 * 64];
  __shared__ __align__(16) unsigned short s_v0[64 * 64];
  __shared__ __align__(16) unsigned short s_v1[64 * 64];
  __shared__ __align__(16) unsigned short s_p[128 * 64];

  attn_pass(qg + base, kg + base, vg + base, outg, b, h, t,
            s_k0, s_k1, s_v0, s_v1, s_p, tid, lane, w, m16, quad);
}

// ---------------------------------------------------------------------------
extern "C" void kernel_launch(void* const* d_in, const int* in_sizes, int n_in,
                              void* d_out, int out_size, void* d_ws, size_t ws_size,
                              hipStream_t stream) {
  (void)in_sizes; (void)n_in; (void)out_size; (void)ws_size;
  const void* x    = d_in[0];
  const void* cosp = d_in[1];
  const void* sinp = d_in[2];
  const void* wqkv = d_in[3];
  const void* wout = d_in[4];

  int* dflag = (int*)d_ws;
  const size_t per = (size_t)BSZ * NH * TSZ * HD;       // 4,194,304 elems
  unsigned short* q = (unsigned short*)((char*)d_ws + 256);
  unsigned short* k = q + per;
  unsigned short* v = k + per;
  unsigned short* attnb = v + per;                      // [B,T,DIM] bf16
  unsigned short* xb   = attnb + (size_t)MROWS * DIMC;  // bf16 copies (fp32 case)
  unsigned short* wqb  = xb + (size_t)MROWS * DIMC;
  unsigned short* wob  = wqb + (size_t)3 * DIMC * DIMC;

  detect_dtype<<<1, 64, 0, stream>>>((const unsigned short*)cosp, dflag);
  cvt_all<<<dim3(4096), dim3(256), 0, stream>>>(
      (const float*)x, (const float*)wqkv, (const float*)wout, xb, wqb, wob, dflag);
  // QKV projection: 128x64 tiles -> 1536 blocks (heavy co-residency)
  gemm_bt_async<1><<<dim3(3 * DIMC / 64, MROWS / 128), dim3(256), 0, stream>>>(
      x, xb, wqkv, wqb, nullptr, cosp, sinp, q, k, v, dflag, 3 * DIMC);
  // causal flash attention: 512 single-tile blocks, longest first, 3 blocks/CU
  attn_fwd_mfma<<<dim3(512), dim3(512), 0, stream>>>(q, k, v, attnb);
  // out-projection: 128x64 tiles -> 512 blocks
  gemm_bt_async<0><<<dim3(DIMC / 64, MROWS / 128), dim3(256), 0, stream>>>(
      attnb, attnb, wout, wob, d_out, nullptr, nullptr,
      nullptr, nullptr, nullptr, dflag, DIMC);
}